// Round 13
// baseline (332.619 us; speedup 1.0000x reference)
//
#include <hip/hip_runtime.h>
#include <hip/hip_bf16.h>

#define LQ 20197
#define NBATCH 2
#define MROWS 40394
#define MR256 ((size_t)MROWS * 256)

typedef __attribute__((ext_vector_type(8))) short bf16x8;
typedef __attribute__((ext_vector_type(4))) float f32x4;
typedef __attribute__((ext_vector_type(2))) _Float16 f16x2;

__device__ __forceinline__ unsigned short f2bf(float f) {
    unsigned u = __float_as_uint(f);
    return (unsigned short)((u + 0x7fff + ((u >> 16) & 1)) >> 16);   // RNE
}
__device__ __forceinline__ float bf2f(unsigned short b) {
    return __uint_as_float((unsigned)b << 16);
}

__device__ __forceinline__ void gload16(const void* g, void* l) {
    __builtin_amdgcn_global_load_lds(
        (const __attribute__((address_space(1))) unsigned int*)g,
        (__attribute__((address_space(3))) unsigned int*)l, 16, 0, 0);
}

__device__ __forceinline__ int swz_k(int n, int kk) {
    return (kk & ~63) | (((((kk >> 3) & 7) ^ (n & 7))) << 3) | (kk & 7);
}

// ---------------- prep: weight transposes (bf16), PRE-SWIZZLED for gload_lds ----------------
__global__ __launch_bounds__(256) void prep_w_k(
    const float* __restrict__ Wv, const float* __restrict__ Wo,
    const float* __restrict__ Wa, const float* __restrict__ Wu,
    const float* __restrict__ W1, const float* __restrict__ W2,
    const float* __restrict__ ba,
    unsigned short* __restrict__ BTv, unsigned short* __restrict__ BTo,
    unsigned short* __restrict__ BTa, unsigned short* __restrict__ BTu,
    unsigned short* __restrict__ BT1, unsigned short* __restrict__ BT2,
    float* __restrict__ battn)
{
    const size_t id0 = (size_t)blockIdx.x * blockDim.x + threadIdx.x;
    const size_t stride = (size_t)gridDim.x * blockDim.x;
    for (size_t i = id0; i < 65536; i += stride) {
        const int n = (int)(i >> 8), kk = (int)(i & 255);
        const int k = swz_k(n, kk);
        BTv[i] = f2bf(Wv[k * 256 + n]);
        BTo[i] = f2bf(Wo[k * 256 + n]);
        BTu[i] = f2bf(Wu[k * 256 + n]);
        BTa[i] = (n < 128) ? f2bf(Wa[k * 128 + n]) : (unsigned short)0;
    }
    for (size_t i = id0; i < 262144; i += stride) {
        const int n = (int)(i >> 8), kk = (int)(i & 255);       // BT1 [1024][256]
        BT1[i] = f2bf(W1[(size_t)swz_k(n, kk) * 1024 + n]);
        const int n2 = (int)(i >> 10), kk2 = (int)(i & 1023);   // BT2 [256][1024]
        BT2[i] = f2bf(W2[(size_t)swz_k(n2, kk2) * 256 + n2]);
    }
    if (id0 < 256) battn[id0] = (id0 < 128) ? ba[id0] : 0.f;
}

// ---------------- fused QKV: value (f16) / loc / attn; BM=128, 512 thr (grid 948) ----------------
__global__ __launch_bounds__(512) void qkv_k(
    const float* __restrict__ keyf, const float* __restrict__ srcf,
    const unsigned short* __restrict__ BT012,
    const float* __restrict__ bval, const float* __restrict__ boff,
    const float* __restrict__ batt, const float* __restrict__ refpts,
    unsigned short* __restrict__ value_o, float* __restrict__ loc_o, float* __restrict__ attn_o)
{
    __shared__ __align__(16) unsigned short As[128 * 64];
    __shared__ __align__(16) unsigned short Bs[256 * 64];

    const int tid = threadIdx.x;
    const int w = tid >> 6, wr = w >> 2, wc = w & 3;
    const int l = tid & 63, lc = l & 15, rg = l >> 4;
    const int wb = tid & ~63;
    const int rowBase = blockIdx.x * 128;
    const int y = blockIdx.y;
    const float* A = (y == 0) ? keyf : srcf;
    const unsigned short* BTb = BT012 + (size_t)y * 65536;
    const float* bias = (y == 0) ? bval : (y == 1) ? boff : batt;

    f32x4 acc[4][4] = {};

    for (int k0 = 0; k0 < 256; k0 += 64) {
        if (k0) __syncthreads();
        #pragma unroll
        for (int p = 0; p < 4; ++p) {
            const int idx = tid + p * 512;
            gload16(BTb + (size_t)(idx >> 3) * 256 + k0 + (idx & 7) * 8,
                    &Bs[(p * 512 + wb) * 8]);
        }
        #pragma unroll
        for (int p = 0; p < 2; ++p) {
            const int idx = tid + p * 512;
            const int r = idx >> 3, s = idx & 7;
            const int row = rowBase + r;
            bf16x8 v = {};
            if (row < MROWS) {
                const float4 v0 = *(const float4*)(A + (size_t)row * 256 + k0 + s * 8);
                const float4 v1 = *(const float4*)(A + (size_t)row * 256 + k0 + s * 8 + 4);
                v[0] = (short)f2bf(v0.x); v[1] = (short)f2bf(v0.y);
                v[2] = (short)f2bf(v0.z); v[3] = (short)f2bf(v0.w);
                v[4] = (short)f2bf(v1.x); v[5] = (short)f2bf(v1.y);
                v[6] = (short)f2bf(v1.z); v[7] = (short)f2bf(v1.w);
            }
            *(bf16x8*)&As[r * 64 + ((s ^ (r & 7)) << 3)] = v;
        }
        __syncthreads();
        #pragma unroll
        for (int kk = 0; kk < 2; ++kk) {
            bf16x8 aF[4], bF[4];
            const int sl = kk * 4 + rg;
            #pragma unroll
            for (int i = 0; i < 4; ++i) {
                const int r = wr * 64 + i * 16 + lc;
                aF[i] = *(const bf16x8*)&As[r * 64 + ((sl ^ (r & 7)) << 3)];
            }
            #pragma unroll
            for (int j = 0; j < 4; ++j) {
                const int n = wc * 64 + j * 16 + lc;
                bF[j] = *(const bf16x8*)&Bs[n * 64 + ((sl ^ (n & 7)) << 3)];
            }
            #pragma unroll
            for (int i = 0; i < 4; ++i)
                #pragma unroll
                for (int j = 0; j < 4; ++j)
                    acc[i][j] = __builtin_amdgcn_mfma_f32_16x16x32_bf16(aF[i], bF[j], acc[i][j], 0, 0, 0);
        }
    }

    if (y == 0) {
        #pragma unroll
        for (int i = 0; i < 4; ++i)
            #pragma unroll
            for (int r4 = 0; r4 < 4; ++r4) {
                const int row = rowBase + wr * 64 + i * 16 + rg * 4 + r4;
                if (row >= MROWS) continue;
                #pragma unroll
                for (int j = 0; j < 4; ++j) {
                    const int col = wc * 64 + j * 16 + lc;
                    const _Float16 h = (_Float16)(acc[i][j][r4] + bias[col]);
                    value_o[(size_t)row * 256 + col] = __builtin_bit_cast(unsigned short, h);
                }
            }
    } else if (y == 1) {
        const float INV[8] = {1.f/152, 1.f/100, 1.f/76, 1.f/50, 1.f/38, 1.f/25, 1.f/19, 1.f/13};
        #pragma unroll
        for (int i = 0; i < 4; ++i)
            #pragma unroll
            for (int r4 = 0; r4 < 4; ++r4) {
                const int row = rowBase + wr * 64 + i * 16 + rg * 4 + r4;
                if (row >= MROWS) continue;
                #pragma unroll
                for (int j = 0; j < 4; ++j) {
                    const int col = wc * 64 + j * 16 + lc;
                    const int lvl = (col >> 4) & 3, xy = col & 1;
                    const float off = acc[i][j][r4] + bias[col];
                    const float ref = refpts[(size_t)row * 8 + lvl * 2 + xy];
                    loc_o[(size_t)row * 256 + col] = ref + off * INV[lvl * 2 + xy];
                }
            }
    } else {
        if (wc >= 2) return;
        #pragma unroll
        for (int i = 0; i < 4; ++i)
            #pragma unroll
            for (int r4 = 0; r4 < 4; ++r4) {
                const int row = rowBase + wr * 64 + i * 16 + rg * 4 + r4;
                float v[4];
                #pragma unroll
                for (int j = 0; j < 4; ++j) v[j] = acc[i][j][r4] + bias[wc * 64 + j * 16 + lc];
                float mA = fmaxf(v[0], v[1]), mB = fmaxf(v[2], v[3]);
                #pragma unroll
                for (int o = 1; o <= 8; o <<= 1) {
                    mA = fmaxf(mA, __shfl_xor(mA, o));
                    mB = fmaxf(mB, __shfl_xor(mB, o));
                }
                float e[4];
                e[0] = __expf(v[0] - mA); e[1] = __expf(v[1] - mA);
                e[2] = __expf(v[2] - mB); e[3] = __expf(v[3] - mB);
                float sA = e[0] + e[1], sB = e[2] + e[3];
                #pragma unroll
                for (int o = 1; o <= 8; o <<= 1) {
                    sA += __shfl_xor(sA, o);
                    sB += __shfl_xor(sB, o);
                }
                if (row >= MROWS) continue;
                #pragma unroll
                for (int j = 0; j < 4; ++j) {
                    const int col = wc * 64 + j * 16 + lc;
                    attn_o[(size_t)row * 128 + col] = e[j] / (j < 2 ? sA : sB);
                }
            }
    }
}

// ---------------- FFN1: h = relu(x@W1+b1); BM=128, 512 thr (grid 1264) ----------------
__global__ __launch_bounds__(512) void ffn1_k(
    const unsigned short* __restrict__ Ap, const unsigned short* __restrict__ BT,
    const float* __restrict__ bias, unsigned short* __restrict__ h0,
    unsigned short* __restrict__ h1)
{
    __shared__ __align__(16) unsigned short As[128 * 64];
    __shared__ __align__(16) unsigned short Bs[256 * 64];

    const int tid = threadIdx.x;
    const int w = tid >> 6, wr = w >> 2, wc = w & 3;
    const int l = tid & 63, lc = l & 15, rg = l >> 4;
    const int wb = tid & ~63;
    const int rowBase = blockIdx.x * 128;
    const unsigned short* BTb = BT + (size_t)blockIdx.y * 65536;
    const bool fullA = (rowBase + 128 <= MROWS);

    f32x4 acc[4][4] = {};

    for (int k0 = 0; k0 < 256; k0 += 64) {
        if (k0) __syncthreads();
        #pragma unroll
        for (int p = 0; p < 4; ++p) {
            const int idx = tid + p * 512;
            gload16(BTb + (size_t)(idx >> 3) * 256 + k0 + (idx & 7) * 8,
                    &Bs[(p * 512 + wb) * 8]);
        }
        if (fullA) {
            #pragma unroll
            for (int p = 0; p < 2; ++p) {
                const int idx = tid + p * 512;
                gload16(Ap + (size_t)(rowBase + (idx >> 3)) * 256 + k0 + (idx & 7) * 8,
                        &As[(p * 512 + wb) * 8]);
            }
        } else {
            #pragma unroll
            for (int p = 0; p < 2; ++p) {
                const int idx = tid + p * 512;
                const int row = rowBase + (idx >> 3);
                bf16x8 v = {};
                if (row < MROWS)
                    v = *(const bf16x8*)(Ap + (size_t)row * 256 + k0 + (idx & 7) * 8);
                *(bf16x8*)&As[idx * 8] = v;
            }
        }
        __syncthreads();
        #pragma unroll
        for (int kk = 0; kk < 2; ++kk) {
            bf16x8 aF[4], bF[4];
            const int sl = kk * 4 + rg;
            #pragma unroll
            for (int i = 0; i < 4; ++i) {
                const int r = wr * 64 + i * 16 + lc;
                aF[i] = *(const bf16x8*)&As[r * 64 + ((sl ^ (r & 7)) << 3)];
            }
            #pragma unroll
            for (int j = 0; j < 4; ++j) {
                const int n = wc * 64 + j * 16 + lc;
                bF[j] = *(const bf16x8*)&Bs[n * 64 + ((sl ^ (n & 7)) << 3)];
            }
            #pragma unroll
            for (int i = 0; i < 4; ++i)
                #pragma unroll
                for (int j = 0; j < 4; ++j)
                    acc[i][j] = __builtin_amdgcn_mfma_f32_16x16x32_bf16(aF[i], bF[j], acc[i][j], 0, 0, 0);
        }
    }

    #pragma unroll
    for (int i = 0; i < 4; ++i)
        #pragma unroll
        for (int r4 = 0; r4 < 4; ++r4) {
            const int row = rowBase + wr * 64 + i * 16 + rg * 4 + r4;
            if (row >= MROWS) continue;
            #pragma unroll
            for (int j = 0; j < 4; ++j) {
                const int colg = blockIdx.y * 256 + wc * 64 + j * 16 + lc;
                const float t = fmaxf(acc[i][j][r4] + bias[colg], 0.f);
                unsigned short* hb = (colg < 512) ? h0 : h1;
                const int lcol = colg & 511;
                const int gg = lcol >> 3, e = lcol & 7;
                const int gs = (gg & 56) | ((gg & 7) ^ (row & 7));
                hb[(size_t)row * 512 + gs * 8 + e] = f2bf(t);
            }
        }
}

// ---------------- LN1: 2-phase prefetched double-buffer; BM=64, 256 thr (grid 632) ----------------
__global__ __launch_bounds__(256) void ln1_k(
    const unsigned short* __restrict__ Ap, const unsigned short* __restrict__ BT,
    const float* __restrict__ bias, const float* __restrict__ aux,
    const float* __restrict__ g, const float* __restrict__ be,
    unsigned short* __restrict__ out)
{
    __shared__ __align__(16) unsigned short As[2][64 * 64];   // 16 KB
    __shared__ __align__(16) unsigned short Bs[2][256 * 64];  // 64 KB  (total 80 KB -> 2 blocks/CU)
    // LN scratch aliased onto As[0] after the K-loop (protected by last __syncthreads)
    float (*ps)[4] = (float (*)[4])(&As[0][0]);
    float (*pq)[4] = (float (*)[4])(&As[0][1024]);
    float* mu_s = (float*)(&As[0][2048]);
    float* rs_s = (float*)(&As[0][2304]);

    const int tid = threadIdx.x;
    const int l = tid & 63, w = tid >> 6;
    const int lc = l & 15, rg = l >> 4;
    const int rowBase = blockIdx.x * 64;
    const int wb = tid & ~63;
    const bool fullA = (rowBase + 64 <= MROWS);

    auto stage = [&](int k0, int b) {
        #pragma unroll
        for (int p = 0; p < 8; ++p) {
            const int idx = tid + p * 256;
            gload16(BT + (size_t)(idx >> 3) * 256 + k0 + (idx & 7) * 8,
                    &Bs[b][(p * 256 + wb) * 8]);
        }
        if (fullA) {
            #pragma unroll
            for (int p = 0; p < 2; ++p) {
                const int idx = tid + p * 256;
                gload16(Ap + (size_t)(rowBase + (idx >> 3)) * 256 + k0 + (idx & 7) * 8,
                        &As[b][(p * 256 + wb) * 8]);
            }
        } else {
            #pragma unroll
            for (int p = 0; p < 2; ++p) {
                const int idx = tid + p * 256;
                const int row = rowBase + (idx >> 3);
                bf16x8 v = {};
                if (row < MROWS)
                    v = *(const bf16x8*)(Ap + (size_t)row * 256 + k0 + (idx & 7) * 8);
                *(bf16x8*)&As[b][idx * 8] = v;
            }
        }
    };

    f32x4 acc[4][4] = {};
    stage(0, 0);
    __syncthreads();

    for (int ks = 0; ks < 4; ++ks) {
        const int b = ks & 1;
        if (ks < 3) stage((ks + 1) * 64, b ^ 1);   // prefetch next tile BEFORE compute
        #pragma unroll
        for (int kk = 0; kk < 2; ++kk) {
            bf16x8 aF[4], bF[4];
            const int sl = kk * 4 + rg;
            #pragma unroll
            for (int i = 0; i < 4; ++i) {
                const int r = i * 16 + lc;
                aF[i] = *(const bf16x8*)&As[b][r * 64 + ((sl ^ (r & 7)) << 3)];
            }
            #pragma unroll
            for (int j = 0; j < 4; ++j) {
                const int n = w * 64 + j * 16 + lc;
                bF[j] = *(const bf16x8*)&Bs[b][n * 64 + ((sl ^ (n & 7)) << 3)];
            }
            #pragma unroll
            for (int i = 0; i < 4; ++i)
                #pragma unroll
                for (int j = 0; j < 4; ++j)
                    acc[i][j] = __builtin_amdgcn_mfma_f32_16x16x32_bf16(aF[i], bF[j], acc[i][j], 0, 0, 0);
        }
        __syncthreads();   // one barrier/step: drains prefetch (covered by compute) + read-protect
    }

    #pragma unroll
    for (int i = 0; i < 4; ++i)
        #pragma unroll
        for (int r4 = 0; r4 < 4; ++r4) {
            const int row = rowBase + i * 16 + rg * 4 + r4;
            float s = 0.f, q = 0.f;
            #pragma unroll
            for (int j = 0; j < 4; ++j) {
                const int col = w * 64 + j * 16 + lc;
                float t = acc[i][j][r4] + bias[col];
                if (row < MROWS) t += aux[(size_t)row * 256 + col];
                acc[i][j][r4] = t;
                s += t; q += t * t;
            }
            #pragma unroll
            for (int o = 1; o <= 8; o <<= 1) { s += __shfl_xor(s, o); q += __shfl_xor(q, o); }
            if (lc == 0) { ps[i * 16 + rg * 4 + r4][w] = s; pq[i * 16 + rg * 4 + r4][w] = q; }
        }
    __syncthreads();
    if (tid < 64) {
        const float s = ps[tid][0] + ps[tid][1] + ps[tid][2] + ps[tid][3];
        const float q = pq[tid][0] + pq[tid][1] + pq[tid][2] + pq[tid][3];
        const float m = s * (1.f / 256.f);
        mu_s[tid] = m;
        rs_s[tid] = rsqrtf(q * (1.f / 256.f) - m * m + 1e-5f);
    }
    __syncthreads();
    #pragma unroll
    for (int i = 0; i < 4; ++i)
        #pragma unroll
        for (int r4 = 0; r4 < 4; ++r4) {
            const int rl = i * 16 + rg * 4 + r4;
            const int row = rowBase + rl;
            if (row >= MROWS) continue;
            const float m = mu_s[rl], r = rs_s[rl];
            #pragma unroll
            for (int j = 0; j < 4; ++j) {
                const int col = w * 64 + j * 16 + lc;
                const int gg = col >> 3, e = col & 7;
                const int gs = (gg & 24) | ((gg & 7) ^ (row & 7));
                out[(size_t)row * 256 + gs * 8 + e] = f2bf((acc[i][j][r4] - m) * r * g[col] + be[col]);
            }
        }
}

// ---------------- FFN2: 2-phase prefetched double-buffer; K=1024, BM=64, 256 thr ----------------
__global__ __launch_bounds__(256) void ffn2_k(
    const unsigned short* __restrict__ h0, const unsigned short* __restrict__ h1,
    const unsigned short* __restrict__ BT2,
    const float* __restrict__ bias, const unsigned short* __restrict__ xb,
    const float* __restrict__ g, const float* __restrict__ be,
    float* __restrict__ out)
{
    __shared__ __align__(16) unsigned short As[2][64 * 64];
    __shared__ __align__(16) unsigned short Bs[2][256 * 64];
    float (*ps)[4] = (float (*)[4])(&As[0][0]);
    float (*pq)[4] = (float (*)[4])(&As[0][1024]);
    float* mu_s = (float*)(&As[0][2048]);
    float* rs_s = (float*)(&As[0][2304]);

    const int tid = threadIdx.x;
    const int l = tid & 63, w = tid >> 6;
    const int lc = l & 15, rg = l >> 4;
    const int rowBase = blockIdx.x * 64;
    const int wb = tid & ~63;
    const bool fullA = (rowBase + 64 <= MROWS);

    auto stage = [&](int kc, int b) {
        #pragma unroll
        for (int p = 0; p < 8; ++p) {
            const int idx = tid + p * 256;
            gload16(BT2 + (size_t)(idx >> 3) * 1024 + kc * 64 + (idx & 7) * 8,
                    &Bs[b][(p * 256 + wb) * 8]);
        }
        const unsigned short* Ab = (kc < 8) ? h0 : h1;
        const int koff = (kc & 7) * 64;
        if (fullA) {
            #pragma unroll
            for (int p = 0; p < 2; ++p) {
                const int idx = tid + p * 256;
                gload16(Ab + (size_t)(rowBase + (idx >> 3)) * 512 + koff + (idx & 7) * 8,
                        &As[b][(p * 256 + wb) * 8]);
            }
        } else {
            #pragma unroll
            for (int p = 0; p < 2; ++p) {
                const int idx = tid + p * 256;
                const int row = rowBase + (idx >> 3);
                bf16x8 v = {};
                if (row < MROWS)
                    v = *(const bf16x8*)(Ab + (size_t)row * 512 + koff + (idx & 7) * 8);
                *(bf16x8*)&As[b][idx * 8] = v;
            }
        }
    };

    f32x4 acc[4][4] = {};
    stage(0, 0);
    __syncthreads();

    for (int kc = 0; kc < 16; ++kc) {
        const int b = kc & 1;
        if (kc < 15) stage(kc + 1, b ^ 1);   // prefetch next tile BEFORE compute
        #pragma unroll
        for (int kk = 0; kk < 2; ++kk) {
            bf16x8 aF[4], bF[4];
            const int sl = kk * 4 + rg;
            #pragma unroll
            for (int i = 0; i < 4; ++i) {
                const int r = i * 16 + lc;
                aF[i] = *(const bf16x8*)&As[b][r * 64 + ((sl ^ (r & 7)) << 3)];
            }
            #pragma unroll
            for (int j = 0; j < 4; ++j) {
                const int n = w * 64 + j * 16 + lc;
                bF[j] = *(const bf16x8*)&Bs[b][n * 64 + ((sl ^ (n & 7)) << 3)];
            }
            #pragma unroll
            for (int i = 0; i < 4; ++i)
                #pragma unroll
                for (int j = 0; j < 4; ++j)
                    acc[i][j] = __builtin_amdgcn_mfma_f32_16x16x32_bf16(aF[i], bF[j], acc[i][j], 0, 0, 0);
        }
        __syncthreads();
    }

    #pragma unroll
    for (int i = 0; i < 4; ++i)
        #pragma unroll
        for (int r4 = 0; r4 < 4; ++r4) {
            const int row = rowBase + i * 16 + rg * 4 + r4;
            float s = 0.f, q = 0.f;
            #pragma unroll
            for (int j = 0; j < 4; ++j) {
                const int col = w * 64 + j * 16 + lc;
                float t = acc[i][j][r4] + bias[col];
                if (row < MROWS) {
                    const int gg = col >> 3, e = col & 7;
                    const int gs = (gg & 24) | ((gg & 7) ^ (row & 7));
                    t += bf2f(xb[(size_t)row * 256 + gs * 8 + e]);
                }
                acc[i][j][r4] = t;
                s += t; q += t * t;
            }
            #pragma unroll
            for (int o = 1; o <= 8; o <<= 1) { s += __shfl_xor(s, o); q += __shfl_xor(q, o); }
            if (lc == 0) { ps[i * 16 + rg * 4 + r4][w] = s; pq[i * 16 + rg * 4 + r4][w] = q; }
        }
    __syncthreads();
    if (tid < 64) {
        const float s = ps[tid][0] + ps[tid][1] + ps[tid][2] + ps[tid][3];
        const float q = pq[tid][0] + pq[tid][1] + pq[tid][2] + pq[tid][3];
        const float m = s * (1.f / 256.f);
        mu_s[tid] = m;
        rs_s[tid] = rsqrtf(q * (1.f / 256.f) - m * m + 1e-5f);
    }
    __syncthreads();
    #pragma unroll
    for (int i = 0; i < 4; ++i)
        #pragma unroll
        for (int r4 = 0; r4 < 4; ++r4) {
            const int rl = i * 16 + rg * 4 + r4;
            const int row = rowBase + rl;
            if (row >= MROWS) continue;
            const float m = mu_s[rl], r = rs_s[rl];
            #pragma unroll
            for (int j = 0; j < 4; ++j) {
                const int col = w * 64 + j * 16 + lc;
                out[(size_t)row * 256 + col] = (acc[i][j][r4] - m) * r * g[col] + be[col];
            }
        }
}

// ---------------- deformable sampling: [q][head][tap][nb] table, b128 write / b64 pair reads ----------------
#define QB2 8
__global__ __launch_bounds__(256, 8) void sample_k(
    const unsigned short* __restrict__ value, const float* __restrict__ loc_i,
    const float* __restrict__ attn_i, unsigned short* __restrict__ samp_o)
{
    constexpr int LVL_H[4] = {100, 50, 25, 13};
    constexpr int LVL_W[4] = {152, 76, 38, 19};
    constexpr int LVL_S[4] = {0, 15200, 19000, 19950};
    const int tid = threadIdx.x;

    const int nwg = gridDim.x;
    const int bid = blockIdx.x;
    const int xcd = bid & 7, lid = bid >> 3;
    const int qq = nwg >> 3, rr = nwg & 7;
    const int sw = (xcd < rr ? xcd * (qq + 1) : rr * (qq + 1) + (xcd - rr) * qq) + lid;
    const int rowBase = sw * QB2;

    __shared__ unsigned sU[QB2][4][33][4];

    #pragma unroll
    for (int it = 0; it < 4; ++it) {
        const int item = tid + it * 256;
        const int qs = item >> 7;
        const int t  = item & 127;
        const int row = rowBase + qs;
        if (row < MROWS) {
            const int lv = (t >> 3) & 3;
            const int n = (row >= LQ) ? 1 : 0;
            const int H = LVL_H[lv], W = LVL_W[lv];
            const float lx = loc_i[(size_t)row * 256 + t * 2 + 0];
            const float ly = loc_i[(size_t)row * 256 + t * 2 + 1];
            const float a  = attn_i[(size_t)row * 128 + t];
            const float x = lx * (float)W - 0.5f;
            const float y = ly * (float)H - 0.5f;
            const float x0f = floorf(x), y0f = floorf(y);
            const float wx = x - x0f, wy = y - y0f;
            const int x0 = (int)x0f, y0 = (int)y0f;
            const int base = n * LQ + LVL_S[lv];
            unsigned e[4];
            #pragma unroll
            for (int nb = 0; nb < 4; ++nb) {
                const int dx = nb & 1, dy = nb >> 1;
                const int xi = x0 + dx, yi = y0 + dy;
                const bool valid = (xi >= 0) & (xi < W) & (yi >= 0) & (yi < H);
                const float wgt = (dx ? wx : 1.f - wx) * (dy ? wy : 1.f - wy) * a;
                const int xc = min(max(xi, 0), W - 1);
                const int yc = min(max(yi, 0), H - 1);
                const unsigned pos = (unsigned)(base + yc * W + xc);
                const _Float16 hw = (_Float16)(valid ? wgt : 0.f);
                e[nb] = (pos << 16) | (unsigned)__builtin_bit_cast(unsigned short, hw);
            }
            *(uint4*)&sU[qs][t >> 5][t & 31][0] = make_uint4(e[0], e[1], e[2], e[3]);
        }
    }
    __syncthreads();

    const int qs = tid >> 5;
    const int c8 = tid & 31;
    const int row = rowBase + qs;
    if (row >= MROWS) return;
    const int m = c8 >> 3;
    const char* vb = (const char*)value + c8 * 16;

    f16x2 A0 = {0, 0}, A1 = {0, 0}, A2 = {0, 0}, A3 = {0, 0};
    #pragma unroll 4
    for (int j = 0; j < 64; ++j) {
        const int t0 = j >> 1, np = (j & 1) << 1;
        const uint2 uu = *(const uint2*)&sU[qs][m][t0][np];
        {
            const unsigned u = uu.x;
            const unsigned off = (u >> 16) << 9;
            const unsigned w2u = __builtin_amdgcn_perm(u, u, 0x01000100);
            const f16x2 w2 = __builtin_bit_cast(f16x2, w2u);
            const uint4 vv = *(const uint4*)(vb + off);
            A0 = __builtin_elementwise_fma(__builtin_bit_cast(f16x2, vv.x), w2, A0);
            A1 = __builtin_elementwise_fma(__builtin_bit_cast(f16x2, vv.y), w2, A1);
            A2 = __builtin_elementwise_fma(__builtin_bit_cast(f16x2, vv.z), w2, A2);
            A3 = __builtin_elementwise_fma(__builtin_bit_cast(f16x2, vv.w), w2, A3);
        }
        {
            const unsigned u = uu.y;
            const unsigned off = (u >> 16) << 9;
            const unsigned w2u = __builtin_amdgcn_perm(u, u, 0x01000100);
            const f16x2 w2 = __builtin_bit_cast(f16x2, w2u);
            const uint4 vv = *(const uint4*)(vb + off);
            A0 = __builtin_elementwise_fma(__builtin_bit_cast(f16x2, vv.x), w2, A0);
            A1 = __builtin_elementwise_fma(__builtin_bit_cast(f16x2, vv.y), w2, A1);
            A2 = __builtin_elementwise_fma(__builtin_bit_cast(f16x2, vv.z), w2, A2);
            A3 = __builtin_elementwise_fma(__builtin_bit_cast(f16x2, vv.w), w2, A3);
        }
    }
    uint4 o;
    o.x = (unsigned)f2bf((float)A0.x) | ((unsigned)f2bf((float)A0.y) << 16);
    o.y = (unsigned)f2bf((float)A1.x) | ((unsigned)f2bf((float)A1.y) << 16);
    o.z = (unsigned)f2bf((float)A2.x) | ((unsigned)f2bf((float)A2.y) << 16);
    o.w = (unsigned)f2bf((float)A3.x) | ((unsigned)f2bf((float)A3.y) << 16);
    const int slot = (c8 & 24) | ((c8 & 7) ^ (row & 7));
    *(uint4*)(samp_o + (size_t)row * 256 + slot * 8) = o;
}

extern "C" void kernel_launch(void* const* d_in, const int* in_sizes, int n_in,
                              void* d_out, int out_size, void* d_ws, size_t ws_size,
                              hipStream_t stream)
{
    const float* src_feat = (const float*)d_in[0];
    const float* refpts   = (const float*)d_in[1];
    const float* key_feat = (const float*)d_in[2];
    const float* W_off  = (const float*)d_in[5];
    const float* b_off  = (const float*)d_in[6];
    const float* W_attn = (const float*)d_in[7];
    const float* b_attn = (const float*)d_in[8];
    const float* W_val  = (const float*)d_in[9];
    const float* b_val  = (const float*)d_in[10];
    const float* W_out  = (const float*)d_in[11];
    const float* b_out  = (const float*)d_in[12];
    const float* W1  = (const float*)d_in[13];
    const float* b1  = (const float*)d_in[14];
    const float* W2  = (const float*)d_in[15];
    const float* b2  = (const float*)d_in[16];
    const float* g1  = (const float*)d_in[17];
    const float* be1 = (const float*)d_in[18];
    const float* g2  = (const float*)d_in[19];
    const float* be2 = (const float*)d_in[20];

    float* out = (float*)d_out;
    float* x_out    = out;
    float* loc_out  = out + MR256;
    float* attn_out = out + 2 * MR256;

    char* ws = (char*)d_ws;
    unsigned short* BTv   = (unsigned short*)(ws + 0);
    unsigned short* BTo   = (unsigned short*)(ws + 131072);
    unsigned short* BTa   = (unsigned short*)(ws + 262144);
    unsigned short* BTu   = (unsigned short*)(ws + 393216);
    unsigned short* BT1   = (unsigned short*)(ws + 524288);
    unsigned short* BT2   = (unsigned short*)(ws + 1048576);
    float*          battn = (float*)(ws + 1572864);
    unsigned short* value = (unsigned short*)(ws + 2097152);              // f16
    unsigned short* samp  = (unsigned short*)(ws + 2097152 + MR256 * 2);  // bf16
    unsigned short* xb    = (unsigned short*)(ws + 2097152 + MR256 * 4);  // bf16
    unsigned short* h0    = value;                       // [M][512] overlays value+samp
    unsigned short* h1    = (unsigned short*)x_out;      // [M][512] overlays x_out

    const int RB  = (MROWS + 63) / 64;     // 632
    const int RB2 = (MROWS + 127) / 128;   // 316

    prep_w_k<<<512, 256, 0, stream>>>(W_val, W_off, W_attn, W_out, W1, W2, b_attn,
                                      BTv, BTo, BTa, BTu, BT1, BT2, battn);
    qkv_k<<<dim3(RB2, 3), 512, 0, stream>>>(key_feat, src_feat, BTv,
                                            b_val, b_off, battn, refpts,
                                            value, loc_out, attn_out);
    sample_k<<<(MROWS + QB2 - 1) / QB2, 256, 0, stream>>>(value, loc_out, attn_out, samp);
    ln1_k<<<RB, 256, 0, stream>>>(samp, BTu, b_out, src_feat, g1, be1, xb);
    ffn1_k<<<dim3(RB2, 4), 512, 0, stream>>>(xb, BT1, b1, h0, h1);
    ffn2_k<<<RB, 256, 0, stream>>>(h0, h1, BT2, b2, xb, g2, be2, x_out);
}

// Round 14
// 315.362 us; speedup vs baseline: 1.0547x; 1.0547x over previous
//
#include <hip/hip_runtime.h>
#include <hip/hip_bf16.h>

#define LQ 20197
#define NBATCH 2
#define MROWS 40394
#define MR256 ((size_t)MROWS * 256)

typedef __attribute__((ext_vector_type(8))) short bf16x8;
typedef __attribute__((ext_vector_type(4))) float f32x4;
typedef __attribute__((ext_vector_type(2))) _Float16 f16x2;

__device__ __forceinline__ unsigned short f2bf(float f) {
    unsigned u = __float_as_uint(f);
    return (unsigned short)((u + 0x7fff + ((u >> 16) & 1)) >> 16);   // RNE
}
__device__ __forceinline__ float bf2f(unsigned short b) {
    return __uint_as_float((unsigned)b << 16);
}

__device__ __forceinline__ void gload16(const void* g, void* l) {
    __builtin_amdgcn_global_load_lds(
        (const __attribute__((address_space(1))) unsigned int*)g,
        (__attribute__((address_space(3))) unsigned int*)l, 16, 0, 0);
}

__device__ __forceinline__ int swz_k(int n, int kk) {
    return (kk & ~63) | (((((kk >> 3) & 7) ^ (n & 7))) << 3) | (kk & 7);
}

// ---------------- prep: weight transposes (bf16), PRE-SWIZZLED for gload_lds ----------------
__global__ __launch_bounds__(256) void prep_w_k(
    const float* __restrict__ Wv, const float* __restrict__ Wo,
    const float* __restrict__ Wa, const float* __restrict__ Wu,
    const float* __restrict__ W1, const float* __restrict__ W2,
    const float* __restrict__ ba,
    unsigned short* __restrict__ BTv, unsigned short* __restrict__ BTo,
    unsigned short* __restrict__ BTa, unsigned short* __restrict__ BTu,
    unsigned short* __restrict__ BT1, unsigned short* __restrict__ BT2,
    float* __restrict__ battn)
{
    const size_t id0 = (size_t)blockIdx.x * blockDim.x + threadIdx.x;
    const size_t stride = (size_t)gridDim.x * blockDim.x;
    for (size_t i = id0; i < 65536; i += stride) {
        const int n = (int)(i >> 8), kk = (int)(i & 255);
        const int k = swz_k(n, kk);
        BTv[i] = f2bf(Wv[k * 256 + n]);
        BTo[i] = f2bf(Wo[k * 256 + n]);
        BTu[i] = f2bf(Wu[k * 256 + n]);
        BTa[i] = (n < 128) ? f2bf(Wa[k * 128 + n]) : (unsigned short)0;
    }
    for (size_t i = id0; i < 262144; i += stride) {
        const int n = (int)(i >> 8), kk = (int)(i & 255);       // BT1 [1024][256]
        BT1[i] = f2bf(W1[(size_t)swz_k(n, kk) * 1024 + n]);
        const int n2 = (int)(i >> 10), kk2 = (int)(i & 1023);   // BT2 [256][1024]
        BT2[i] = f2bf(W2[(size_t)swz_k(n2, kk2) * 256 + n2]);
    }
    if (id0 < 256) battn[id0] = (id0 < 128) ? ba[id0] : 0.f;
}

// ---------------- fused QKV: value (f16) / loc / attn; BM=128, 512 thr (grid 948) ----------------
__global__ __launch_bounds__(512) void qkv_k(
    const float* __restrict__ keyf, const float* __restrict__ srcf,
    const unsigned short* __restrict__ BT012,
    const float* __restrict__ bval, const float* __restrict__ boff,
    const float* __restrict__ batt, const float* __restrict__ refpts,
    unsigned short* __restrict__ value_o, float* __restrict__ loc_o, float* __restrict__ attn_o)
{
    __shared__ __align__(16) unsigned short As[128 * 64];
    __shared__ __align__(16) unsigned short Bs[256 * 64];

    const int tid = threadIdx.x;
    const int w = tid >> 6, wr = w >> 2, wc = w & 3;
    const int l = tid & 63, lc = l & 15, rg = l >> 4;
    const int wb = tid & ~63;
    const int rowBase = blockIdx.x * 128;
    const int y = blockIdx.y;
    const float* A = (y == 0) ? keyf : srcf;
    const unsigned short* BTb = BT012 + (size_t)y * 65536;
    const float* bias = (y == 0) ? bval : (y == 1) ? boff : batt;

    f32x4 acc[4][4] = {};

    for (int k0 = 0; k0 < 256; k0 += 64) {
        if (k0) __syncthreads();
        #pragma unroll
        for (int p = 0; p < 4; ++p) {
            const int idx = tid + p * 512;
            gload16(BTb + (size_t)(idx >> 3) * 256 + k0 + (idx & 7) * 8,
                    &Bs[(p * 512 + wb) * 8]);
        }
        #pragma unroll
        for (int p = 0; p < 2; ++p) {
            const int idx = tid + p * 512;
            const int r = idx >> 3, s = idx & 7;
            const int row = rowBase + r;
            bf16x8 v = {};
            if (row < MROWS) {
                const float4 v0 = *(const float4*)(A + (size_t)row * 256 + k0 + s * 8);
                const float4 v1 = *(const float4*)(A + (size_t)row * 256 + k0 + s * 8 + 4);
                v[0] = (short)f2bf(v0.x); v[1] = (short)f2bf(v0.y);
                v[2] = (short)f2bf(v0.z); v[3] = (short)f2bf(v0.w);
                v[4] = (short)f2bf(v1.x); v[5] = (short)f2bf(v1.y);
                v[6] = (short)f2bf(v1.z); v[7] = (short)f2bf(v1.w);
            }
            *(bf16x8*)&As[r * 64 + ((s ^ (r & 7)) << 3)] = v;
        }
        __syncthreads();
        #pragma unroll
        for (int kk = 0; kk < 2; ++kk) {
            bf16x8 aF[4], bF[4];
            const int sl = kk * 4 + rg;
            #pragma unroll
            for (int i = 0; i < 4; ++i) {
                const int r = wr * 64 + i * 16 + lc;
                aF[i] = *(const bf16x8*)&As[r * 64 + ((sl ^ (r & 7)) << 3)];
            }
            #pragma unroll
            for (int j = 0; j < 4; ++j) {
                const int n = wc * 64 + j * 16 + lc;
                bF[j] = *(const bf16x8*)&Bs[n * 64 + ((sl ^ (n & 7)) << 3)];
            }
            #pragma unroll
            for (int i = 0; i < 4; ++i)
                #pragma unroll
                for (int j = 0; j < 4; ++j)
                    acc[i][j] = __builtin_amdgcn_mfma_f32_16x16x32_bf16(aF[i], bF[j], acc[i][j], 0, 0, 0);
        }
    }

    if (y == 0) {
        #pragma unroll
        for (int i = 0; i < 4; ++i)
            #pragma unroll
            for (int r4 = 0; r4 < 4; ++r4) {
                const int row = rowBase + wr * 64 + i * 16 + rg * 4 + r4;
                if (row >= MROWS) continue;
                #pragma unroll
                for (int j = 0; j < 4; ++j) {
                    const int col = wc * 64 + j * 16 + lc;
                    const _Float16 h = (_Float16)(acc[i][j][r4] + bias[col]);
                    value_o[(size_t)row * 256 + col] = __builtin_bit_cast(unsigned short, h);
                }
            }
    } else if (y == 1) {
        const float INV[8] = {1.f/152, 1.f/100, 1.f/76, 1.f/50, 1.f/38, 1.f/25, 1.f/19, 1.f/13};
        #pragma unroll
        for (int i = 0; i < 4; ++i)
            #pragma unroll
            for (int r4 = 0; r4 < 4; ++r4) {
                const int row = rowBase + wr * 64 + i * 16 + rg * 4 + r4;
                if (row >= MROWS) continue;
                #pragma unroll
                for (int j = 0; j < 4; ++j) {
                    const int col = wc * 64 + j * 16 + lc;
                    const int lvl = (col >> 4) & 3, xy = col & 1;
                    const float off = acc[i][j][r4] + bias[col];
                    const float ref = refpts[(size_t)row * 8 + lvl * 2 + xy];
                    loc_o[(size_t)row * 256 + col] = ref + off * INV[lvl * 2 + xy];
                }
            }
    } else {
        if (wc >= 2) return;
        #pragma unroll
        for (int i = 0; i < 4; ++i)
            #pragma unroll
            for (int r4 = 0; r4 < 4; ++r4) {
                const int row = rowBase + wr * 64 + i * 16 + rg * 4 + r4;
                float v[4];
                #pragma unroll
                for (int j = 0; j < 4; ++j) v[j] = acc[i][j][r4] + bias[wc * 64 + j * 16 + lc];
                float mA = fmaxf(v[0], v[1]), mB = fmaxf(v[2], v[3]);
                #pragma unroll
                for (int o = 1; o <= 8; o <<= 1) {
                    mA = fmaxf(mA, __shfl_xor(mA, o));
                    mB = fmaxf(mB, __shfl_xor(mB, o));
                }
                float e[4];
                e[0] = __expf(v[0] - mA); e[1] = __expf(v[1] - mA);
                e[2] = __expf(v[2] - mB); e[3] = __expf(v[3] - mB);
                float sA = e[0] + e[1], sB = e[2] + e[3];
                #pragma unroll
                for (int o = 1; o <= 8; o <<= 1) {
                    sA += __shfl_xor(sA, o);
                    sB += __shfl_xor(sB, o);
                }
                if (row >= MROWS) continue;
                #pragma unroll
                for (int j = 0; j < 4; ++j) {
                    const int col = wc * 64 + j * 16 + lc;
                    attn_o[(size_t)row * 128 + col] = e[j] / (j < 2 ? sA : sB);
                }
            }
    }
}

// ---------------- FFN1: h = relu(x@W1+b1); BM=128, 512 thr (grid 1264) ----------------
__global__ __launch_bounds__(512) void ffn1_k(
    const unsigned short* __restrict__ Ap, const unsigned short* __restrict__ BT,
    const float* __restrict__ bias, unsigned short* __restrict__ h0,
    unsigned short* __restrict__ h1)
{
    __shared__ __align__(16) unsigned short As[128 * 64];
    __shared__ __align__(16) unsigned short Bs[256 * 64];

    const int tid = threadIdx.x;
    const int w = tid >> 6, wr = w >> 2, wc = w & 3;
    const int l = tid & 63, lc = l & 15, rg = l >> 4;
    const int wb = tid & ~63;
    const int rowBase = blockIdx.x * 128;
    const unsigned short* BTb = BT + (size_t)blockIdx.y * 65536;
    const bool fullA = (rowBase + 128 <= MROWS);

    f32x4 acc[4][4] = {};

    for (int k0 = 0; k0 < 256; k0 += 64) {
        if (k0) __syncthreads();
        #pragma unroll
        for (int p = 0; p < 4; ++p) {
            const int idx = tid + p * 512;
            gload16(BTb + (size_t)(idx >> 3) * 256 + k0 + (idx & 7) * 8,
                    &Bs[(p * 512 + wb) * 8]);
        }
        if (fullA) {
            #pragma unroll
            for (int p = 0; p < 2; ++p) {
                const int idx = tid + p * 512;
                gload16(Ap + (size_t)(rowBase + (idx >> 3)) * 256 + k0 + (idx & 7) * 8,
                        &As[(p * 512 + wb) * 8]);
            }
        } else {
            #pragma unroll
            for (int p = 0; p < 2; ++p) {
                const int idx = tid + p * 512;
                const int row = rowBase + (idx >> 3);
                bf16x8 v = {};
                if (row < MROWS)
                    v = *(const bf16x8*)(Ap + (size_t)row * 256 + k0 + (idx & 7) * 8);
                *(bf16x8*)&As[idx * 8] = v;
            }
        }
        __syncthreads();
        #pragma unroll
        for (int kk = 0; kk < 2; ++kk) {
            bf16x8 aF[4], bF[4];
            const int sl = kk * 4 + rg;
            #pragma unroll
            for (int i = 0; i < 4; ++i) {
                const int r = wr * 64 + i * 16 + lc;
                aF[i] = *(const bf16x8*)&As[r * 64 + ((sl ^ (r & 7)) << 3)];
            }
            #pragma unroll
            for (int j = 0; j < 4; ++j) {
                const int n = wc * 64 + j * 16 + lc;
                bF[j] = *(const bf16x8*)&Bs[n * 64 + ((sl ^ (n & 7)) << 3)];
            }
            #pragma unroll
            for (int i = 0; i < 4; ++i)
                #pragma unroll
                for (int j = 0; j < 4; ++j)
                    acc[i][j] = __builtin_amdgcn_mfma_f32_16x16x32_bf16(aF[i], bF[j], acc[i][j], 0, 0, 0);
        }
    }

    #pragma unroll
    for (int i = 0; i < 4; ++i)
        #pragma unroll
        for (int r4 = 0; r4 < 4; ++r4) {
            const int row = rowBase + wr * 64 + i * 16 + rg * 4 + r4;
            if (row >= MROWS) continue;
            #pragma unroll
            for (int j = 0; j < 4; ++j) {
                const int colg = blockIdx.y * 256 + wc * 64 + j * 16 + lc;
                const float t = fmaxf(acc[i][j][r4] + bias[colg], 0.f);
                unsigned short* hb = (colg < 512) ? h0 : h1;
                const int lcol = colg & 511;
                const int gg = lcol >> 3, e = lcol & 7;
                const int gs = (gg & 56) | ((gg & 7) ^ (row & 7));
                hb[(size_t)row * 512 + gs * 8 + e] = f2bf(t);
            }
        }
}

// ---------------- LN1: xb = LN(src + samp@Wu+bu); BM=64, 256 thr (grid 632) ----------------
__global__ __launch_bounds__(256) void ln1_k(
    const unsigned short* __restrict__ Ap, const unsigned short* __restrict__ BT,
    const float* __restrict__ bias, const float* __restrict__ aux,
    const float* __restrict__ g, const float* __restrict__ be,
    unsigned short* __restrict__ out)
{
    __shared__ __align__(16) unsigned short As[64 * 64];
    __shared__ __align__(16) unsigned short Bs[256 * 64];
    __shared__ float ps[64][4], pq[64][4];
    __shared__ float mu_s[64], rs_s[64];

    const int tid = threadIdx.x;
    const int l = tid & 63, w = tid >> 6;
    const int lc = l & 15, rg = l >> 4;
    const int rowBase = blockIdx.x * 64;
    const int wb = tid & ~63;
    const bool fullA = (rowBase + 64 <= MROWS);

    f32x4 acc[4][4] = {};

    for (int k0 = 0; k0 < 256; k0 += 64) {
        if (k0) __syncthreads();
        #pragma unroll
        for (int p = 0; p < 8; ++p) {
            const int idx = tid + p * 256;
            gload16(BT + (size_t)(idx >> 3) * 256 + k0 + (idx & 7) * 8,
                    &Bs[(p * 256 + wb) * 8]);
        }
        if (fullA) {
            #pragma unroll
            for (int p = 0; p < 2; ++p) {
                const int idx = tid + p * 256;
                gload16(Ap + (size_t)(rowBase + (idx >> 3)) * 256 + k0 + (idx & 7) * 8,
                        &As[(p * 256 + wb) * 8]);
            }
        } else {
            #pragma unroll
            for (int p = 0; p < 2; ++p) {
                const int idx = tid + p * 256;
                const int row = rowBase + (idx >> 3);
                bf16x8 v = {};
                if (row < MROWS)
                    v = *(const bf16x8*)(Ap + (size_t)row * 256 + k0 + (idx & 7) * 8);
                *(bf16x8*)&As[idx * 8] = v;
            }
        }
        __syncthreads();
        #pragma unroll
        for (int kk = 0; kk < 2; ++kk) {
            bf16x8 aF[4], bF[4];
            const int sl = kk * 4 + rg;
            #pragma unroll
            for (int i = 0; i < 4; ++i) {
                const int r = i * 16 + lc;
                aF[i] = *(const bf16x8*)&As[r * 64 + ((sl ^ (r & 7)) << 3)];
            }
            #pragma unroll
            for (int j = 0; j < 4; ++j) {
                const int n = w * 64 + j * 16 + lc;
                bF[j] = *(const bf16x8*)&Bs[n * 64 + ((sl ^ (n & 7)) << 3)];
            }
            #pragma unroll
            for (int i = 0; i < 4; ++i)
                #pragma unroll
                for (int j = 0; j < 4; ++j)
                    acc[i][j] = __builtin_amdgcn_mfma_f32_16x16x32_bf16(aF[i], bF[j], acc[i][j], 0, 0, 0);
        }
    }

    #pragma unroll
    for (int i = 0; i < 4; ++i)
        #pragma unroll
        for (int r4 = 0; r4 < 4; ++r4) {
            const int row = rowBase + i * 16 + rg * 4 + r4;
            float s = 0.f, q = 0.f;
            #pragma unroll
            for (int j = 0; j < 4; ++j) {
                const int col = w * 64 + j * 16 + lc;
                float t = acc[i][j][r4] + bias[col];
                if (row < MROWS) t += aux[(size_t)row * 256 + col];
                acc[i][j][r4] = t;
                s += t; q += t * t;
            }
            #pragma unroll
            for (int o = 1; o <= 8; o <<= 1) { s += __shfl_xor(s, o); q += __shfl_xor(q, o); }
            if (lc == 0) { ps[i * 16 + rg * 4 + r4][w] = s; pq[i * 16 + rg * 4 + r4][w] = q; }
        }
    __syncthreads();
    if (tid < 64) {
        const float s = ps[tid][0] + ps[tid][1] + ps[tid][2] + ps[tid][3];
        const float q = pq[tid][0] + pq[tid][1] + pq[tid][2] + pq[tid][3];
        const float m = s * (1.f / 256.f);
        mu_s[tid] = m;
        rs_s[tid] = rsqrtf(q * (1.f / 256.f) - m * m + 1e-5f);
    }
    __syncthreads();
    #pragma unroll
    for (int i = 0; i < 4; ++i)
        #pragma unroll
        for (int r4 = 0; r4 < 4; ++r4) {
            const int rl = i * 16 + rg * 4 + r4;
            const int row = rowBase + rl;
            if (row >= MROWS) continue;
            const float m = mu_s[rl], r = rs_s[rl];
            #pragma unroll
            for (int j = 0; j < 4; ++j) {
                const int col = w * 64 + j * 16 + lc;
                const int gg = col >> 3, e = col & 7;
                const int gs = (gg & 24) | ((gg & 7) ^ (row & 7));
                out[(size_t)row * 256 + gs * 8 + e] = f2bf((acc[i][j][r4] - m) * r * g[col] + be[col]);
            }
        }
}

// ---------------- FFN2: out = LN2(xb + h@W2 + b2); BM=64, 256 thr (grid 632) ----------------
__global__ __launch_bounds__(256) void ffn2_k(
    const unsigned short* __restrict__ h0, const unsigned short* __restrict__ h1,
    const unsigned short* __restrict__ BT2,
    const float* __restrict__ bias, const unsigned short* __restrict__ xb,
    const float* __restrict__ g, const float* __restrict__ be,
    float* __restrict__ out)
{
    __shared__ __align__(16) unsigned short As[64 * 64];
    __shared__ __align__(16) unsigned short Bs[256 * 64];
    __shared__ float ps[64][4], pq[64][4];
    __shared__ float mu_s[64], rs_s[64];

    const int tid = threadIdx.x;
    const int l = tid & 63, w = tid >> 6;
    const int lc = l & 15, rg = l >> 4;
    const int rowBase = blockIdx.x * 64;
    const int wb = tid & ~63;
    const bool fullA = (rowBase + 64 <= MROWS);

    f32x4 acc[4][4] = {};

    for (int kc = 0; kc < 16; ++kc) {
        if (kc) __syncthreads();
        #pragma unroll
        for (int p = 0; p < 8; ++p) {
            const int idx = tid + p * 256;
            gload16(BT2 + (size_t)(idx >> 3) * 1024 + kc * 64 + (idx & 7) * 8,
                    &Bs[(p * 256 + wb) * 8]);
        }
        const unsigned short* Ab = (kc < 8) ? h0 : h1;
        const int koff = (kc & 7) * 64;
        if (fullA) {
            #pragma unroll
            for (int p = 0; p < 2; ++p) {
                const int idx = tid + p * 256;
                gload16(Ab + (size_t)(rowBase + (idx >> 3)) * 512 + koff + (idx & 7) * 8,
                        &As[(p * 256 + wb) * 8]);
            }
        } else {
            #pragma unroll
            for (int p = 0; p < 2; ++p) {
                const int idx = tid + p * 256;
                const int row = rowBase + (idx >> 3);
                bf16x8 v = {};
                if (row < MROWS) v = *(const bf16x8*)(Ab + (size_t)row * 512 + koff + (idx & 7) * 8);
                *(bf16x8*)&As[idx * 8] = v;
            }
        }
        __syncthreads();
        #pragma unroll
        for (int kk = 0; kk < 2; ++kk) {
            bf16x8 aF[4], bF[4];
            const int sl = kk * 4 + rg;
            #pragma unroll
            for (int i = 0; i < 4; ++i) {
                const int r = i * 16 + lc;
                aF[i] = *(const bf16x8*)&As[r * 64 + ((sl ^ (r & 7)) << 3)];
            }
            #pragma unroll
            for (int j = 0; j < 4; ++j) {
                const int n = w * 64 + j * 16 + lc;
                bF[j] = *(const bf16x8*)&Bs[n * 64 + ((sl ^ (n & 7)) << 3)];
            }
            #pragma unroll
            for (int i = 0; i < 4; ++i)
                #pragma unroll
                for (int j = 0; j < 4; ++j)
                    acc[i][j] = __builtin_amdgcn_mfma_f32_16x16x32_bf16(aF[i], bF[j], acc[i][j], 0, 0, 0);
        }
    }

    #pragma unroll
    for (int i = 0; i < 4; ++i)
        #pragma unroll
        for (int r4 = 0; r4 < 4; ++r4) {
            const int row = rowBase + i * 16 + rg * 4 + r4;
            float s = 0.f, q = 0.f;
            #pragma unroll
            for (int j = 0; j < 4; ++j) {
                const int col = w * 64 + j * 16 + lc;
                float t = acc[i][j][r4] + bias[col];
                if (row < MROWS) {
                    const int gg = col >> 3, e = col & 7;
                    const int gs = (gg & 24) | ((gg & 7) ^ (row & 7));
                    t += bf2f(xb[(size_t)row * 256 + gs * 8 + e]);
                }
                acc[i][j][r4] = t;
                s += t; q += t * t;
            }
            #pragma unroll
            for (int o = 1; o <= 8; o <<= 1) { s += __shfl_xor(s, o); q += __shfl_xor(q, o); }
            if (lc == 0) { ps[i * 16 + rg * 4 + r4][w] = s; pq[i * 16 + rg * 4 + r4][w] = q; }
        }
    __syncthreads();
    if (tid < 64) {
        const float s = ps[tid][0] + ps[tid][1] + ps[tid][2] + ps[tid][3];
        const float q = pq[tid][0] + pq[tid][1] + pq[tid][2] + pq[tid][3];
        const float m = s * (1.f / 256.f);
        mu_s[tid] = m;
        rs_s[tid] = rsqrtf(q * (1.f / 256.f) - m * m + 1e-5f);
    }
    __syncthreads();
    #pragma unroll
    for (int i = 0; i < 4; ++i)
        #pragma unroll
        for (int r4 = 0; r4 < 4; ++r4) {
            const int rl = i * 16 + rg * 4 + r4;
            const int row = rowBase + rl;
            if (row >= MROWS) continue;
            const float m = mu_s[rl], r = rs_s[rl];
            #pragma unroll
            for (int j = 0; j < 4; ++j) {
                const int col = w * 64 + j * 16 + lc;
                out[(size_t)row * 256 + col] = (acc[i][j][r4] - m) * r * g[col] + be[col];
            }
        }
}

// ---------------- deformable sampling: [q][head][tap][nb] table, b128 write / b64 pair reads ----------------
#define QB2 8
__global__ __launch_bounds__(256, 8) void sample_k(
    const unsigned short* __restrict__ value, const float* __restrict__ loc_i,
    const float* __restrict__ attn_i, unsigned short* __restrict__ samp_o)
{
    constexpr int LVL_H[4] = {100, 50, 25, 13};
    constexpr int LVL_W[4] = {152, 76, 38, 19};
    constexpr int LVL_S[4] = {0, 15200, 19000, 19950};
    const int tid = threadIdx.x;

    // bijective XCD-chunked swizzle (m204)
    const int nwg = gridDim.x;
    const int bid = blockIdx.x;
    const int xcd = bid & 7, lid = bid >> 3;
    const int qq = nwg >> 3, rr = nwg & 7;
    const int sw = (xcd < rr ? xcd * (qq + 1) : rr * (qq + 1) + (xcd - rr) * qq) + lid;
    const int rowBase = sw * QB2;

    __shared__ unsigned sU[QB2][4][33][4];

    #pragma unroll
    for (int it = 0; it < 4; ++it) {
        const int item = tid + it * 256;
        const int qs = item >> 7;
        const int t  = item & 127;
        const int row = rowBase + qs;
        if (row < MROWS) {
            const int lv = (t >> 3) & 3;
            const int n = (row >= LQ) ? 1 : 0;
            const int H = LVL_H[lv], W = LVL_W[lv];
            const float lx = loc_i[(size_t)row * 256 + t * 2 + 0];
            const float ly = loc_i[(size_t)row * 256 + t * 2 + 1];
            const float a  = attn_i[(size_t)row * 128 + t];
            const float x = lx * (float)W - 0.5f;
            const float y = ly * (float)H - 0.5f;
            const float x0f = floorf(x), y0f = floorf(y);
            const float wx = x - x0f, wy = y - y0f;
            const int x0 = (int)x0f, y0 = (int)y0f;
            const int base = n * LQ + LVL_S[lv];
            unsigned e[4];
            #pragma unroll
            for (int nb = 0; nb < 4; ++nb) {
                const int dx = nb & 1, dy = nb >> 1;
                const int xi = x0 + dx, yi = y0 + dy;
                const bool valid = (xi >= 0) & (xi < W) & (yi >= 0) & (yi < H);
                const float wgt = (dx ? wx : 1.f - wx) * (dy ? wy : 1.f - wy) * a;
                const int xc = min(max(xi, 0), W - 1);
                const int yc = min(max(yi, 0), H - 1);
                const unsigned pos = (unsigned)(base + yc * W + xc);
                const _Float16 hw = (_Float16)(valid ? wgt : 0.f);
                e[nb] = (pos << 16) | (unsigned)__builtin_bit_cast(unsigned short, hw);
            }
            *(uint4*)&sU[qs][t >> 5][t & 31][0] = make_uint4(e[0], e[1], e[2], e[3]);
        }
    }
    __syncthreads();

    const int qs = tid >> 5;
    const int c8 = tid & 31;
    const int row = rowBase + qs;
    if (row >= MROWS) return;
    const int m = c8 >> 3;
    const char* vb = (const char*)value + c8 * 16;

    f16x2 A0 = {0, 0}, A1 = {0, 0}, A2 = {0, 0}, A3 = {0, 0};
    #pragma unroll 4
    for (int j = 0; j < 64; ++j) {
        const int t0 = j >> 1, np = (j & 1) << 1;
        const uint2 uu = *(const uint2*)&sU[qs][m][t0][np];
        {
            const unsigned u = uu.x;
            const unsigned off = (u >> 16) << 9;
            const unsigned w2u = __builtin_amdgcn_perm(u, u, 0x01000100);
            const f16x2 w2 = __builtin_bit_cast(f16x2, w2u);
            const uint4 vv = *(const uint4*)(vb + off);
            A0 = __builtin_elementwise_fma(__builtin_bit_cast(f16x2, vv.x), w2, A0);
            A1 = __builtin_elementwise_fma(__builtin_bit_cast(f16x2, vv.y), w2, A1);
            A2 = __builtin_elementwise_fma(__builtin_bit_cast(f16x2, vv.z), w2, A2);
            A3 = __builtin_elementwise_fma(__builtin_bit_cast(f16x2, vv.w), w2, A3);
        }
        {
            const unsigned u = uu.y;
            const unsigned off = (u >> 16) << 9;
            const unsigned w2u = __builtin_amdgcn_perm(u, u, 0x01000100);
            const f16x2 w2 = __builtin_bit_cast(f16x2, w2u);
            const uint4 vv = *(const uint4*)(vb + off);
            A0 = __builtin_elementwise_fma(__builtin_bit_cast(f16x2, vv.x), w2, A0);
            A1 = __builtin_elementwise_fma(__builtin_bit_cast(f16x2, vv.y), w2, A1);
            A2 = __builtin_elementwise_fma(__builtin_bit_cast(f16x2, vv.z), w2, A2);
            A3 = __builtin_elementwise_fma(__builtin_bit_cast(f16x2, vv.w), w2, A3);
        }
    }
    uint4 o;
    o.x = (unsigned)f2bf((float)A0.x) | ((unsigned)f2bf((float)A0.y) << 16);
    o.y = (unsigned)f2bf((float)A1.x) | ((unsigned)f2bf((float)A1.y) << 16);
    o.z = (unsigned)f2bf((float)A2.x) | ((unsigned)f2bf((float)A2.y) << 16);
    o.w = (unsigned)f2bf((float)A3.x) | ((unsigned)f2bf((float)A3.y) << 16);
    const int slot = (c8 & 24) | ((c8 & 7) ^ (row & 7));
    *(uint4*)(samp_o + (size_t)row * 256 + slot * 8) = o;
}

extern "C" void kernel_launch(void* const* d_in, const int* in_sizes, int n_in,
                              void* d_out, int out_size, void* d_ws, size_t ws_size,
                              hipStream_t stream)
{
    const float* src_feat = (const float*)d_in[0];
    const float* refpts   = (const float*)d_in[1];
    const float* key_feat = (const float*)d_in[2];
    const float* W_off  = (const float*)d_in[5];
    const float* b_off  = (const float*)d_in[6];
    const float* W_attn = (const float*)d_in[7];
    const float* b_attn = (const float*)d_in[8];
    const float* W_val  = (const float*)d_in[9];
    const float* b_val  = (const float*)d_in[10];
    const float* W_out  = (const float*)d_in[11];
    const float* b_out  = (const float*)d_in[12];
    const float* W1  = (const float*)d_in[13];
    const float* b1  = (const float*)d_in[14];
    const float* W2  = (const float*)d_in[15];
    const float* b2  = (const float*)d_in[16];
    const float* g1  = (const float*)d_in[17];
    const float* be1 = (const float*)d_in[18];
    const float* g2  = (const float*)d_in[19];
    const float* be2 = (const float*)d_in[20];

    float* out = (float*)d_out;
    float* x_out    = out;
    float* loc_out  = out + MR256;
    float* attn_out = out + 2 * MR256;

    char* ws = (char*)d_ws;
    unsigned short* BTv   = (unsigned short*)(ws + 0);
    unsigned short* BTo   = (unsigned short*)(ws + 131072);
    unsigned short* BTa   = (unsigned short*)(ws + 262144);
    unsigned short* BTu   = (unsigned short*)(ws + 393216);
    unsigned short* BT1   = (unsigned short*)(ws + 524288);
    unsigned short* BT2   = (unsigned short*)(ws + 1048576);
    float*          battn = (float*)(ws + 1572864);
    unsigned short* value = (unsigned short*)(ws + 2097152);              // f16
    unsigned short* samp  = (unsigned short*)(ws + 2097152 + MR256 * 2);  // bf16
    unsigned short* xb    = (unsigned short*)(ws + 2097152 + MR256 * 4);  // bf16
    unsigned short* h0    = value;                       // [M][512] overlays value+samp
    unsigned short* h1    = (unsigned short*)x_out;      // [M][512] overlays x_out

    const int RB  = (MROWS + 63) / 64;     // 632
    const int RB2 = (MROWS + 127) / 128;   // 316

    prep_w_k<<<512, 256, 0, stream>>>(W_val, W_off, W_attn, W_out, W1, W2, b_attn,
                                      BTv, BTo, BTa, BTu, BT1, BT2, battn);
    qkv_k<<<dim3(RB2, 3), 512, 0, stream>>>(key_feat, src_feat, BTv,
                                            b_val, b_off, battn, refpts,
                                            value, loc_out, attn_out);
    sample_k<<<(MROWS + QB2 - 1) / QB2, 256, 0, stream>>>(value, loc_out, attn_out, samp);
    ln1_k<<<RB, 256, 0, stream>>>(samp, BTu, b_out, src_feat, g1, be1, xb);
    ffn1_k<<<dim3(RB2, 4), 512, 0, stream>>>(xb, BT1, b1, h0, h1);
    ffn2_k<<<RB, 256, 0, stream>>>(h0, h1, BT2, b2, xb, g2, be2, x_out);
}